// Round 1
// baseline (2193.143 us; speedup 1.0000x reference)
//
#include <hip/hip_runtime.h>
#include <hip/hip_bf16.h>

#define DFEAT 256

// ---------------------------------------------------------------------------
// CSR build: histogram -> inclusive scan -> cursor scatter
// ---------------------------------------------------------------------------
__global__ void hist_kernel(const int* __restrict__ dst, int nE, int* __restrict__ P) {
    for (int e = blockIdx.x * blockDim.x + threadIdx.x; e < nE; e += gridDim.x * blockDim.x) {
        atomicAdd(&P[dst[e] + 1], 1);
    }
}

// single-block inclusive scan with carry over 1024-chunks
__global__ void scan_inclusive(int* __restrict__ a, int n) {
    __shared__ int buf[1024];
    __shared__ int carry;
    int tid = threadIdx.x;
    if (tid == 0) carry = 0;
    __syncthreads();
    for (int base = 0; base < n; base += 1024) {
        int i = base + tid;
        int v = (i < n) ? a[i] : 0;
        buf[tid] = v;
        __syncthreads();
        for (int off = 1; off < 1024; off <<= 1) {
            int t = (tid >= off) ? buf[tid - off] : 0;
            __syncthreads();
            buf[tid] += t;
            __syncthreads();
        }
        int inc = buf[tid] + carry;
        if (i < n) a[i] = inc;
        __syncthreads();
        if (tid == 1023) carry = inc;
        __syncthreads();
    }
}

__global__ void copy_int(const int* __restrict__ src, int* __restrict__ dst, int n) {
    for (int i = blockIdx.x * blockDim.x + threadIdx.x; i < n; i += gridDim.x * blockDim.x)
        dst[i] = src[i];
}

__global__ void fill_kernel(const int* __restrict__ dst, int nE,
                            int* __restrict__ cursor, int* __restrict__ eidx) {
    for (int e = blockIdx.x * blockDim.x + threadIdx.x; e < nE; e += gridDim.x * blockDim.x) {
        int pos = atomicAdd(&cursor[dst[e]], 1);
        eidx[pos] = e;
    }
}

// ---------------------------------------------------------------------------
// Aggregation: one wave (64 lanes) per dst row; lane owns 4 consecutive floats
// mean[d, :] = (1/max(cnt,1)) * sum_{e in row d} w[e] * xsrc[src[e], :]
// ---------------------------------------------------------------------------
__global__ __launch_bounds__(256) void aggregate_kernel(
    const float* __restrict__ xsrc, const int* __restrict__ src,
    const float* __restrict__ w, const int* __restrict__ rowptr,
    const int* __restrict__ eidx, float* __restrict__ mean, int ndst)
{
    int wid  = (blockIdx.x * blockDim.x + threadIdx.x) >> 6;
    int lane = threadIdx.x & 63;
    if (wid >= ndst) return;
    int beg = rowptr[wid], end = rowptr[wid + 1];
    const int col = lane * 4;
    float4 acc = {0.f, 0.f, 0.f, 0.f};
    for (int j = beg; j < end; ++j) {
        int e = eidx[j];
        int s = src[e];
        float wt = w[e];
        float4 v = *reinterpret_cast<const float4*>(xsrc + (size_t)s * DFEAT + col);
        acc.x += wt * v.x; acc.y += wt * v.y; acc.z += wt * v.z; acc.w += wt * v.w;
    }
    float inv = (end > beg) ? 1.0f / (float)(end - beg) : 0.0f;
    acc.x *= inv; acc.y *= inv; acc.z *= inv; acc.w *= inv;
    *reinterpret_cast<float4*>(mean + (size_t)wid * DFEAT + col) = acc;
}

// ---------------------------------------------------------------------------
// Fused GEMM: out[i,:] = epilogue( A[i,:]@Wl + B[i,:]@Wr + bias )
//   RELU_RES: out = resid + relu(acc+bias)   else: out = acc+bias
// Block = 256 threads, 32 rows x 256 cols, full-row ownership -> in-place
// (out aliasing A) is safe.
// ---------------------------------------------------------------------------
#define BM 32
#define KC 16
template<bool RELU_RES>
__global__ __launch_bounds__(256) void gemm_fused(
    const float* __restrict__ A, const float* __restrict__ B,
    const float* __restrict__ Wl, const float* __restrict__ Wr,
    const float* __restrict__ bias, const float* __restrict__ resid,
    float* __restrict__ out, int n)
{
    __shared__ float sW[KC][DFEAT];
    __shared__ float sA[BM][KC];
    const int tid = threadIdx.x;
    const int bm = blockIdx.x * BM;
    const int tx = tid & 63;   // col group: cols tx*4 .. tx*4+3
    const int ty = tid >> 6;   // row group: rows ty*8 .. ty*8+7

    float acc[8][4];
    #pragma unroll
    for (int i = 0; i < 8; ++i)
        #pragma unroll
        for (int j = 0; j < 4; ++j) acc[i][j] = 0.f;

    const float* Ms[2] = {A, B};
    const float* Ws[2] = {Wl, Wr};

    for (int m = 0; m < 2; ++m) {
        const float* Mat = Ms[m];
        const float* W   = Ws[m];
        for (int k0 = 0; k0 < DFEAT; k0 += KC) {
            // stage W chunk [KC][256]: 1024 float4, 4 per thread
            #pragma unroll
            for (int q = 0; q < 4; ++q) {
                int f  = tid + q * 256;     // float4 index
                int kr = f >> 6;
                int c4 = f & 63;
                *reinterpret_cast<float4*>(&sW[kr][c4 * 4]) =
                    *reinterpret_cast<const float4*>(W + (size_t)(k0 + kr) * DFEAT + c4 * 4);
            }
            // stage A chunk [BM][KC]: 256 float2, 1 per thread
            {
                int f   = tid;             // float2 index
                int r   = f >> 3;
                int kk  = (f & 7) * 2;
                int row = bm + r;
                float2 v;
                if (row < n)
                    v = *reinterpret_cast<const float2*>(Mat + (size_t)row * DFEAT + k0 + kk);
                else
                    v = make_float2(0.f, 0.f);
                *reinterpret_cast<float2*>(&sA[r][kk]) = v;
            }
            __syncthreads();
            #pragma unroll
            for (int k = 0; k < KC; ++k) {
                float4 wv = *reinterpret_cast<const float4*>(&sW[k][tx * 4]);
                #pragma unroll
                for (int i = 0; i < 8; ++i) {
                    float a = sA[ty * 8 + i][k];
                    acc[i][0] += a * wv.x;
                    acc[i][1] += a * wv.y;
                    acc[i][2] += a * wv.z;
                    acc[i][3] += a * wv.w;
                }
            }
            __syncthreads();
        }
    }

    float4 bv = *reinterpret_cast<const float4*>(bias + tx * 4);
    #pragma unroll
    for (int i = 0; i < 8; ++i) {
        int row = bm + ty * 8 + i;
        if (row >= n) continue;
        float4 o;
        o.x = acc[i][0] + bv.x;
        o.y = acc[i][1] + bv.y;
        o.z = acc[i][2] + bv.z;
        o.w = acc[i][3] + bv.w;
        if (RELU_RES) {
            float4 rv = *reinterpret_cast<const float4*>(resid + (size_t)row * DFEAT + tx * 4);
            o.x = rv.x + fmaxf(o.x, 0.f);
            o.y = rv.y + fmaxf(o.y, 0.f);
            o.z = rv.z + fmaxf(o.z, 0.f);
            o.w = rv.w + fmaxf(o.w, 0.f);
        }
        *reinterpret_cast<float4*>(out + (size_t)row * DFEAT + tx * 4) = o;
    }
}

// ---------------------------------------------------------------------------
extern "C" void kernel_launch(void* const* d_in, const int* in_sizes, int n_in,
                              void* d_out, int out_size, void* d_ws, size_t ws_size,
                              hipStream_t stream) {
    const float* x_user  = (const float*)d_in[0];
    const float* x_movie = (const float*)d_in[1];
    const int*   src_um  = (const int*)d_in[2];
    const int*   dst_um  = (const int*)d_in[3];
    const float* w_um    = (const float*)d_in[4];
    const int*   src_mu  = (const int*)d_in[5];
    const int*   dst_mu  = (const int*)d_in[6];
    const float* w_mu    = (const float*)d_in[7];
    const float* c1_um_Wl = (const float*)d_in[8];
    const float* c1_um_Wr = (const float*)d_in[9];
    const float* c1_um_b  = (const float*)d_in[10];
    const float* c1_mu_Wl = (const float*)d_in[11];
    const float* c1_mu_Wr = (const float*)d_in[12];
    const float* c1_mu_b  = (const float*)d_in[13];
    const float* c2_um_Wl = (const float*)d_in[14];
    const float* c2_um_Wr = (const float*)d_in[15];
    const float* c2_um_b  = (const float*)d_in[16];
    const float* c2_mu_Wl = (const float*)d_in[17];
    const float* c2_mu_Wr = (const float*)d_in[18];
    const float* c2_mu_b  = (const float*)d_in[19];

    const int NU = in_sizes[0] / DFEAT;   // 100000
    const int NM = in_sizes[1] / DFEAT;   // 20000
    const int E_um = in_sizes[2];         // 1M
    const int E_mu = in_sizes[5];         // 1M

    // d_out doubles as mean buffers before the final in-place GEMMs
    float* mean_user  = (float*)d_out;                          // [NU, 256]
    float* mean_movie = (float*)d_out + (size_t)NU * DFEAT;     // [NM, 256]

    // workspace carve
    char* p = (char*)d_ws;
    auto carve = [&](size_t bytes) { char* r = p; p += (bytes + 255) & ~(size_t)255; return r; };
    int* rowptr_m = (int*)carve((size_t)(NM + 1) * 4);
    int* rowptr_u = (int*)carve((size_t)(NU + 1) * 4);
    int* cursor_m = (int*)carve((size_t)NM * 4);
    int* cursor_u = (int*)carve((size_t)NU * 4);
    int* eidx_m   = (int*)carve((size_t)E_um * 4);
    int* eidx_u   = (int*)carve((size_t)E_mu * 4);
    float* r_user  = (float*)carve((size_t)NU * DFEAT * 4);
    float* r_movie = (float*)carve((size_t)NM * DFEAT * 4);

    // ---- CSR build (edges reused by both layers) ----
    hipMemsetAsync(rowptr_m, 0, (size_t)(NM + 1) * 4, stream);
    hipMemsetAsync(rowptr_u, 0, (size_t)(NU + 1) * 4, stream);
    hist_kernel<<<2048, 256, 0, stream>>>(dst_um, E_um, rowptr_m);
    hist_kernel<<<2048, 256, 0, stream>>>(dst_mu, E_mu, rowptr_u);
    scan_inclusive<<<1, 1024, 0, stream>>>(rowptr_m, NM + 1);
    scan_inclusive<<<1, 1024, 0, stream>>>(rowptr_u, NU + 1);
    copy_int<<<256, 256, 0, stream>>>(rowptr_m, cursor_m, NM);
    copy_int<<<256, 256, 0, stream>>>(rowptr_u, cursor_u, NU);
    fill_kernel<<<2048, 256, 0, stream>>>(dst_um, E_um, cursor_m, eidx_m);
    fill_kernel<<<2048, 256, 0, stream>>>(dst_mu, E_mu, cursor_u, eidx_u);

    const int aggB = 256;
    // ---- layer 1 ----
    aggregate_kernel<<<(NM + 3) / 4, aggB, 0, stream>>>(x_user, src_um, w_um, rowptr_m, eidx_m, mean_movie, NM);
    aggregate_kernel<<<(NU + 3) / 4, aggB, 0, stream>>>(x_movie, src_mu, w_mu, rowptr_u, eidx_u, mean_user, NU);
    gemm_fused<true><<<(NM + BM - 1) / BM, 256, 0, stream>>>(
        mean_movie, x_movie, c1_um_Wl, c1_um_Wr, c1_um_b, x_movie, r_movie, NM);
    gemm_fused<true><<<(NU + BM - 1) / BM, 256, 0, stream>>>(
        mean_user, x_user, c1_mu_Wl, c1_mu_Wr, c1_mu_b, x_user, r_user, NU);

    // ---- layer 2 ----
    aggregate_kernel<<<(NM + 3) / 4, aggB, 0, stream>>>(r_user, src_um, w_um, rowptr_m, eidx_m, mean_movie, NM);
    aggregate_kernel<<<(NU + 3) / 4, aggB, 0, stream>>>(r_movie, src_mu, w_mu, rowptr_u, eidx_u, mean_user, NU);
    // in-place over A (full-row block ownership makes this safe)
    gemm_fused<false><<<(NM + BM - 1) / BM, 256, 0, stream>>>(
        mean_movie, r_movie, c2_um_Wl, c2_um_Wr, c2_um_b, nullptr, mean_movie, NM);
    gemm_fused<false><<<(NU + BM - 1) / BM, 256, 0, stream>>>(
        mean_user, r_user, c2_mu_Wl, c2_mu_Wr, c2_mu_b, nullptr, mean_user, NU);
}

// Round 2
// 1361.902 us; speedup vs baseline: 1.6104x; 1.6104x over previous
//
#include <hip/hip_runtime.h>
#include <hip/hip_bf16.h>

#define DFEAT 256

typedef __bf16 bf16x8 __attribute__((ext_vector_type(8)));
typedef __bf16 bf16x4 __attribute__((ext_vector_type(4)));
typedef float  f32x4  __attribute__((ext_vector_type(4)));

// ---------------------------------------------------------------------------
// CSR build: histogram -> inclusive scan -> cursor scatter
// ---------------------------------------------------------------------------
__global__ void hist_kernel(const int* __restrict__ dst, int nE, int* __restrict__ P) {
    for (int e = blockIdx.x * blockDim.x + threadIdx.x; e < nE; e += gridDim.x * blockDim.x)
        atomicAdd(&P[dst[e] + 1], 1);
}

__global__ void scan_inclusive(int* __restrict__ a, int n) {
    __shared__ int buf[1024];
    __shared__ int carry;
    int tid = threadIdx.x;
    if (tid == 0) carry = 0;
    __syncthreads();
    for (int base = 0; base < n; base += 1024) {
        int i = base + tid;
        int v = (i < n) ? a[i] : 0;
        buf[tid] = v;
        __syncthreads();
        for (int off = 1; off < 1024; off <<= 1) {
            int t = (tid >= off) ? buf[tid - off] : 0;
            __syncthreads();
            buf[tid] += t;
            __syncthreads();
        }
        int inc = buf[tid] + carry;
        if (i < n) a[i] = inc;
        __syncthreads();
        if (tid == 1023) carry = inc;
        __syncthreads();
    }
}

__global__ void copy_int(const int* __restrict__ src, int* __restrict__ dst, int n) {
    for (int i = blockIdx.x * blockDim.x + threadIdx.x; i < n; i += gridDim.x * blockDim.x)
        dst[i] = src[i];
}

__global__ void fill_kernel(const int* __restrict__ dst, int nE,
                            int* __restrict__ cursor, int* __restrict__ eidx) {
    for (int e = blockIdx.x * blockDim.x + threadIdx.x; e < nE; e += gridDim.x * blockDim.x) {
        int pos = atomicAdd(&cursor[dst[e]], 1);
        eidx[pos] = e;
    }
}

// ---------------------------------------------------------------------------
// f32 -> bf16 bulk convert (8 elems / thread)
// ---------------------------------------------------------------------------
__global__ __launch_bounds__(256) void f32_to_bf16_kernel(
    const float* __restrict__ in, __bf16* __restrict__ out, int n8)
{
    for (int i = blockIdx.x * blockDim.x + threadIdx.x; i < n8; i += gridDim.x * blockDim.x) {
        float4 a = *reinterpret_cast<const float4*>(in + (size_t)i * 8);
        float4 b = *reinterpret_cast<const float4*>(in + (size_t)i * 8 + 4);
        bf16x8 v;
        v[0] = (__bf16)a.x; v[1] = (__bf16)a.y; v[2] = (__bf16)a.z; v[3] = (__bf16)a.w;
        v[4] = (__bf16)b.x; v[5] = (__bf16)b.y; v[6] = (__bf16)b.z; v[7] = (__bf16)b.w;
        *reinterpret_cast<bf16x8*>(out + (size_t)i * 8) = v;
    }
}

// Build WcatT[n][k] (bf16, [256][512]) with k<256 -> Wl[k][n], k>=256 -> Wr[k-256][n]
__global__ __launch_bounds__(256) void wtrans_kernel(
    const float* __restrict__ Wl, const float* __restrict__ Wr, __bf16* __restrict__ out)
{
    int t = blockIdx.x * blockDim.x + threadIdx.x;   // 256*512 threads
    if (t >= 256 * 512) return;
    int n = t >> 9;
    int k = t & 511;
    float v = (k < 256) ? Wl[(size_t)k * 256 + n] : Wr[(size_t)(k - 256) * 256 + n];
    out[t] = (__bf16)v;
}

// ---------------------------------------------------------------------------
// Aggregation (bf16 features): one wave per dst row, lane owns 4 bf16 cols
// ---------------------------------------------------------------------------
__global__ __launch_bounds__(256) void aggregate_bf16(
    const __bf16* __restrict__ xsrc, const int* __restrict__ src,
    const float* __restrict__ w, const int* __restrict__ rowptr,
    const int* __restrict__ eidx, __bf16* __restrict__ mean, int ndst)
{
    int wid  = (blockIdx.x * blockDim.x + threadIdx.x) >> 6;
    int lane = threadIdx.x & 63;
    if (wid >= ndst) return;
    int beg = rowptr[wid], end = rowptr[wid + 1];
    const int col = lane * 4;
    float ax = 0.f, ay = 0.f, az = 0.f, aw = 0.f;
    for (int j = beg; j < end; ++j) {
        int e = eidx[j];
        int s = src[e];
        float wt = w[e];
        bf16x4 v = *reinterpret_cast<const bf16x4*>(xsrc + (size_t)s * DFEAT + col);
        ax += wt * (float)v[0];
        ay += wt * (float)v[1];
        az += wt * (float)v[2];
        aw += wt * (float)v[3];
    }
    float inv = (end > beg) ? 1.0f / (float)(end - beg) : 0.0f;
    bf16x4 o;
    o[0] = (__bf16)(ax * inv); o[1] = (__bf16)(ay * inv);
    o[2] = (__bf16)(az * inv); o[3] = (__bf16)(aw * inv);
    *reinterpret_cast<bf16x4*>(mean + (size_t)wid * DFEAT + col) = o;
}

// ---------------------------------------------------------------------------
// MFMA GEMM:  out[i,:] = epi( A[i,:]@Wl + B[i,:]@Wr + bias )
// K=512 concat: chunks 0,1 read A (k 0..255 -> Wl rows), chunks 2,3 read B.
// WT is [256 n][512 k] bf16.  Block: 256 thr = 4 waves; tile BM=64 x BN=256;
// wave w owns cols [w*64, w*64+64).  BK=128 per chunk staged in LDS via
// global_load_lds(16B) with pre-swizzled source (byte ^= (row&7)<<4).
// EPI==1: r = resid + relu(acc+bias), bf16 out.  EPI==0: f32 out = acc+bias.
// ---------------------------------------------------------------------------
template<int EPI>
__global__ __launch_bounds__(256) void gemm_mfma(
    const __bf16* __restrict__ A, const __bf16* __restrict__ B,
    const __bf16* __restrict__ WT, const float* __restrict__ bias,
    const __bf16* __restrict__ resid, void* __restrict__ outv, int n)
{
    __shared__ char sAb[64 * 256];   // 64 rows x 128 k x bf16 = 16 KB

    const int tid  = threadIdx.x;
    const int lane = tid & 63;
    const int wv   = tid >> 6;          // wave 0..3
    const int lo   = lane & 15;
    const int hi   = lane >> 4;         // 0..3
    const int brow = blockIdx.x * 64;
    const int wcol = wv * 64;
    const int nm1  = n - 1;

    f32x4 acc[4][4];
    #pragma unroll
    for (int i = 0; i < 4; ++i)
        #pragma unroll
        for (int j = 0; j < 4; ++j) acc[i][j] = (f32x4){0.f, 0.f, 0.f, 0.f};

    for (int chunk = 0; chunk < 4; ++chunk) {
        const __bf16* mat = (chunk < 2) ? A : B;
        const int koff = (chunk & 1) * 256;          // byte offset within 512B row
        // ---- stage A-chunk [64][128] bf16 into LDS (swizzled source, linear dest)
        #pragma unroll
        for (int q = 0; q < 4; ++q) {
            int p    = q * 256 + tid;                // 16B slot index, wave-contiguous
            int row  = p >> 4;
            int slot = p & 15;
            int grow = brow + row; if (grow > nm1) grow = nm1;
            int srcoff = (slot * 16) ^ ((row & 7) << 4);
            const char* g = reinterpret_cast<const char*>(mat) + (size_t)grow * 512 + koff + srcoff;
            char* l = sAb + p * 16;
            __builtin_amdgcn_global_load_lds(
                (const __attribute__((address_space(1))) void*)g,
                (__attribute__((address_space(3))) void*)l, 16, 0, 0);
        }
        __syncthreads();

        // ---- compute: 4 k-tiles x (4 m x 4 n) MFMA
        const size_t wkbase = (size_t)chunk * 128;   // k element base into WT rows
        #pragma unroll
        for (int kt = 0; kt < 4; ++kt) {
            bf16x8 bfr[4];
            #pragma unroll
            for (int nn = 0; nn < 4; ++nn) {
                const __bf16* bp = WT + (size_t)(wcol + nn * 16 + lo) * 512
                                      + wkbase + kt * 32 + hi * 8;
                bfr[nn] = *reinterpret_cast<const bf16x8*>(bp);
            }
            #pragma unroll
            for (int mm = 0; mm < 4; ++mm) {
                int rl = mm * 16 + lo;
                int kb = kt * 64 + hi * 16;
                const bf16x8 a = *reinterpret_cast<const bf16x8*>(
                    sAb + rl * 256 + (kb ^ ((rl & 7) << 4)));
                #pragma unroll
                for (int nn = 0; nn < 4; ++nn)
                    acc[mm][nn] = __builtin_amdgcn_mfma_f32_16x16x32_bf16(
                        a, bfr[nn], acc[mm][nn], 0, 0, 0);
            }
        }
        __syncthreads();
    }

    // ---- epilogue: D row = (lane>>4)*4 + reg, col = lane&15  (m89-verified)
    #pragma unroll
    for (int mm = 0; mm < 4; ++mm) {
        #pragma unroll
        for (int nn = 0; nn < 4; ++nn) {
            int col = wcol + nn * 16 + lo;
            float bv = bias[col];
            #pragma unroll
            for (int r = 0; r < 4; ++r) {
                int grow = brow + mm * 16 + hi * 4 + r;
                if (grow >= n) continue;
                float v = acc[mm][nn][r] + bv;
                if (EPI == 1) {
                    float rv = (float)resid[(size_t)grow * DFEAT + col];
                    ((__bf16*)outv)[(size_t)grow * DFEAT + col] =
                        (__bf16)(rv + fmaxf(v, 0.f));
                } else {
                    ((float*)outv)[(size_t)grow * DFEAT + col] = v;
                }
            }
        }
    }
}

// ---------------------------------------------------------------------------
extern "C" void kernel_launch(void* const* d_in, const int* in_sizes, int n_in,
                              void* d_out, int out_size, void* d_ws, size_t ws_size,
                              hipStream_t stream) {
    const float* x_user  = (const float*)d_in[0];
    const float* x_movie = (const float*)d_in[1];
    const int*   src_um  = (const int*)d_in[2];
    const int*   dst_um  = (const int*)d_in[3];
    const float* w_um    = (const float*)d_in[4];
    const int*   src_mu  = (const int*)d_in[5];
    const int*   dst_mu  = (const int*)d_in[6];
    const float* w_mu    = (const float*)d_in[7];
    const float* c1_um_Wl = (const float*)d_in[8];
    const float* c1_um_Wr = (const float*)d_in[9];
    const float* c1_um_b  = (const float*)d_in[10];
    const float* c1_mu_Wl = (const float*)d_in[11];
    const float* c1_mu_Wr = (const float*)d_in[12];
    const float* c1_mu_b  = (const float*)d_in[13];
    const float* c2_um_Wl = (const float*)d_in[14];
    const float* c2_um_Wr = (const float*)d_in[15];
    const float* c2_um_b  = (const float*)d_in[16];
    const float* c2_mu_Wl = (const float*)d_in[17];
    const float* c2_mu_Wr = (const float*)d_in[18];
    const float* c2_mu_b  = (const float*)d_in[19];

    const int NU = in_sizes[0] / DFEAT;   // 100000
    const int NM = in_sizes[1] / DFEAT;   // 20000
    const int E_um = in_sizes[2];         // 1M
    const int E_mu = in_sizes[5];         // 1M

    // ---- workspace carve (~133 MB) ----
    char* p = (char*)d_ws;
    auto carve = [&](size_t bytes) { char* r = p; p += (bytes + 255) & ~(size_t)255; return r; };
    int* rowptr_m = (int*)carve((size_t)(NM + 1) * 4);
    int* rowptr_u = (int*)carve((size_t)(NU + 1) * 4);
    int* cursor_m = (int*)carve((size_t)NM * 4);
    int* cursor_u = (int*)carve((size_t)NU * 4);
    int* eidx_m   = (int*)carve((size_t)E_um * 4);
    int* eidx_u   = (int*)carve((size_t)E_mu * 4);
    __bf16* xu_bf = (__bf16*)carve((size_t)NU * DFEAT * 2);  // later reused as mean2_user
    __bf16* xm_bf = (__bf16*)carve((size_t)NM * DFEAT * 2);  // later reused as mean2_movie
    __bf16* ru_bf = (__bf16*)carve((size_t)NU * DFEAT * 2);
    __bf16* rm_bf = (__bf16*)carve((size_t)NM * DFEAT * 2);
    __bf16* wt_c1um = (__bf16*)carve(256 * 512 * 2);
    __bf16* wt_c1mu = (__bf16*)carve(256 * 512 * 2);
    __bf16* wt_c2um = (__bf16*)carve(256 * 512 * 2);
    __bf16* wt_c2mu = (__bf16*)carve(256 * 512 * 2);

    // layer-1 means live in d_out (bf16), overwritten by final f32 GEMM output
    __bf16* mean1_u = (__bf16*)d_out;                          // 51.2 MB
    __bf16* mean1_m = (__bf16*)d_out + (size_t)NU * DFEAT;     // 10.24 MB
    float* out_user  = (float*)d_out;
    float* out_movie = (float*)d_out + (size_t)NU * DFEAT;

    // ---- CSR build (shared by both layers) ----
    hipMemsetAsync(rowptr_m, 0, (size_t)(NM + 1) * 4, stream);
    hipMemsetAsync(rowptr_u, 0, (size_t)(NU + 1) * 4, stream);
    hist_kernel<<<2048, 256, 0, stream>>>(dst_um, E_um, rowptr_m);
    hist_kernel<<<2048, 256, 0, stream>>>(dst_mu, E_mu, rowptr_u);
    scan_inclusive<<<1, 1024, 0, stream>>>(rowptr_m, NM + 1);
    scan_inclusive<<<1, 1024, 0, stream>>>(rowptr_u, NU + 1);
    copy_int<<<256, 256, 0, stream>>>(rowptr_m, cursor_m, NM);
    copy_int<<<256, 256, 0, stream>>>(rowptr_u, cursor_u, NU);
    fill_kernel<<<2048, 256, 0, stream>>>(dst_um, E_um, cursor_m, eidx_m);
    fill_kernel<<<2048, 256, 0, stream>>>(dst_mu, E_mu, cursor_u, eidx_u);

    // ---- precompute bf16 features + transposed weights ----
    f32_to_bf16_kernel<<<2048, 256, 0, stream>>>(x_user, xu_bf, NU * DFEAT / 8);
    f32_to_bf16_kernel<<<2048, 256, 0, stream>>>(x_movie, xm_bf, NM * DFEAT / 8);
    wtrans_kernel<<<512, 256, 0, stream>>>(c1_um_Wl, c1_um_Wr, wt_c1um);
    wtrans_kernel<<<512, 256, 0, stream>>>(c1_mu_Wl, c1_mu_Wr, wt_c1mu);
    wtrans_kernel<<<512, 256, 0, stream>>>(c2_um_Wl, c2_um_Wr, wt_c2um);
    wtrans_kernel<<<512, 256, 0, stream>>>(c2_mu_Wl, c2_mu_Wr, wt_c2mu);

    // ---- layer 1 ----
    aggregate_bf16<<<(NM + 3) / 4, 256, 0, stream>>>(xu_bf, src_um, w_um, rowptr_m, eidx_m, mean1_m, NM);
    aggregate_bf16<<<(NU + 3) / 4, 256, 0, stream>>>(xm_bf, src_mu, w_mu, rowptr_u, eidx_u, mean1_u, NU);
    gemm_mfma<1><<<(NM + 63) / 64, 256, 0, stream>>>(mean1_m, xm_bf, wt_c1um, c1_um_b, xm_bf, rm_bf, NM);
    gemm_mfma<1><<<(NU + 63) / 64, 256, 0, stream>>>(mean1_u, xu_bf, wt_c1mu, c1_mu_b, xu_bf, ru_bf, NU);

    // ---- layer 2 (means reuse the dead x_bf buffers) ----
    __bf16* mean2_m = xm_bf;
    __bf16* mean2_u = xu_bf;
    aggregate_bf16<<<(NM + 3) / 4, 256, 0, stream>>>(ru_bf, src_um, w_um, rowptr_m, eidx_m, mean2_m, NM);
    aggregate_bf16<<<(NU + 3) / 4, 256, 0, stream>>>(rm_bf, src_mu, w_mu, rowptr_u, eidx_u, mean2_u, NU);
    gemm_mfma<0><<<(NM + 63) / 64, 256, 0, stream>>>(mean2_m, rm_bf, wt_c2um, c2_um_b, nullptr, out_movie, NM);
    gemm_mfma<0><<<(NU + 63) / 64, 256, 0, stream>>>(mean2_u, ru_bf, wt_c2mu, c2_mu_b, nullptr, out_user, NU);
}

// Round 3
// 801.419 us; speedup vs baseline: 2.7366x; 1.6994x over previous
//
#include <hip/hip_runtime.h>
#include <hip/hip_bf16.h>

#define DFEAT 256

typedef __bf16 bf16x8 __attribute__((ext_vector_type(8)));
typedef __bf16 bf16x4 __attribute__((ext_vector_type(4)));
typedef float  f32x4  __attribute__((ext_vector_type(4)));

// ---------------------------------------------------------------------------
// CSR build: histogram -> hierarchical scan -> cursor scatter (sorted records)
// ---------------------------------------------------------------------------
__global__ void hist_kernel(const int* __restrict__ dst, int nE, int* __restrict__ P) {
    for (int e = blockIdx.x * blockDim.x + threadIdx.x; e < nE; e += gridDim.x * blockDim.x)
        atomicAdd(&P[dst[e] + 1], 1);
}

// Phase A: per-block inclusive scan of 2048 elems (256 thr x 8), write block sums
__global__ __launch_bounds__(256) void scan_block(int* __restrict__ a, int n, int* __restrict__ bsum) {
    __shared__ int wsum[4];
    const int tid = threadIdx.x;
    const int lane = tid & 63, wv = tid >> 6;
    const int idx = blockIdx.x * 2048 + tid * 8;
    int v[8];
    #pragma unroll
    for (int i = 0; i < 8; ++i) v[i] = (idx + i < n) ? a[idx + i] : 0;
    #pragma unroll
    for (int i = 1; i < 8; ++i) v[i] += v[i - 1];
    int tsum = v[7];
    int sc = tsum;
    #pragma unroll
    for (int off = 1; off < 64; off <<= 1) {
        int t = __shfl_up(sc, off);
        if (lane >= off) sc += t;
    }
    if (lane == 63) wsum[wv] = sc;
    __syncthreads();
    int wadd = 0;
    for (int w2 = 0; w2 < wv; ++w2) wadd += wsum[w2];
    int texcl = sc - tsum + wadd;
    #pragma unroll
    for (int i = 0; i < 8; ++i)
        if (idx + i < n) a[idx + i] = v[i] + texcl;
    if (tid == 255) bsum[blockIdx.x] = sc + wadd;
}

// Phase B: single-wave inclusive scan of block sums (nb <= 64)
__global__ void scan_sums(int* __restrict__ bsum, int nb) {
    int lane = threadIdx.x;
    int v = (lane < nb) ? bsum[lane] : 0;
    #pragma unroll
    for (int off = 1; off < 64; off <<= 1) {
        int t = __shfl_up(v, off);
        if (lane >= off) v += t;
    }
    if (lane < nb) bsum[lane] = v;
}

// Phase C: add exclusive block prefix
__global__ __launch_bounds__(256) void scan_add(int* __restrict__ a, int n, const int* __restrict__ bsum) {
    if (blockIdx.x == 0) return;
    int add = bsum[blockIdx.x - 1];
    int idx = blockIdx.x * 2048 + threadIdx.x * 8;
    #pragma unroll
    for (int i = 0; i < 8; ++i)
        if (idx + i < n) a[idx + i] += add;
}

__global__ void copy_int(const int* __restrict__ src, int* __restrict__ dst, int n) {
    for (int i = blockIdx.x * blockDim.x + threadIdx.x; i < n; i += gridDim.x * blockDim.x)
        dst[i] = src[i];
}

// scatter (src,w) into dst-sorted record arrays
__global__ void fill_kernel(const int* __restrict__ dst, const int* __restrict__ src,
                            const float* __restrict__ w, int nE,
                            int* __restrict__ cursor,
                            int* __restrict__ rsrc, float* __restrict__ rw) {
    for (int e = blockIdx.x * blockDim.x + threadIdx.x; e < nE; e += gridDim.x * blockDim.x) {
        int pos = atomicAdd(&cursor[dst[e]], 1);
        rsrc[pos] = src[e];
        rw[pos]   = w[e];
    }
}

// ---------------------------------------------------------------------------
// f32 -> bf16 bulk convert (8 elems / thread)
// ---------------------------------------------------------------------------
__global__ __launch_bounds__(256) void f32_to_bf16_kernel(
    const float* __restrict__ in, __bf16* __restrict__ out, int n8)
{
    for (int i = blockIdx.x * blockDim.x + threadIdx.x; i < n8; i += gridDim.x * blockDim.x) {
        float4 a = *reinterpret_cast<const float4*>(in + (size_t)i * 8);
        float4 b = *reinterpret_cast<const float4*>(in + (size_t)i * 8 + 4);
        bf16x8 v;
        v[0] = (__bf16)a.x; v[1] = (__bf16)a.y; v[2] = (__bf16)a.z; v[3] = (__bf16)a.w;
        v[4] = (__bf16)b.x; v[5] = (__bf16)b.y; v[6] = (__bf16)b.z; v[7] = (__bf16)b.w;
        *reinterpret_cast<bf16x8*>(out + (size_t)i * 8) = v;
    }
}

// Build WcatT[n][k] (bf16, [256][512]) with k<256 -> Wl[k][n], k>=256 -> Wr[k-256][n]
__global__ __launch_bounds__(256) void wtrans_kernel(
    const float* __restrict__ Wl, const float* __restrict__ Wr, __bf16* __restrict__ out)
{
    int t = blockIdx.x * blockDim.x + threadIdx.x;
    if (t >= 256 * 512) return;
    int n = t >> 9;
    int k = t & 511;
    float v = (k < 256) ? Wl[(size_t)k * 256 + n] : Wr[(size_t)(k - 256) * 256 + n];
    out[t] = (__bf16)v;
}

// ---------------------------------------------------------------------------
// Aggregation: one wave per dst row; batch 64 edges (coalesced metadata load,
// readlane broadcast), 8 row-gathers in flight.
// ---------------------------------------------------------------------------
__global__ __launch_bounds__(256) void aggregate_bf16(
    const __bf16* __restrict__ xsrc, const int* __restrict__ rsrc,
    const float* __restrict__ rw, const int* __restrict__ rowptr,
    __bf16* __restrict__ mean, int ndst)
{
    int wid  = (blockIdx.x * blockDim.x + threadIdx.x) >> 6;
    int lane = threadIdx.x & 63;
    if (wid >= ndst) return;
    int beg = rowptr[wid], end = rowptr[wid + 1];
    const __bf16* xcol = xsrc + lane * 4;
    float ax = 0.f, ay = 0.f, az = 0.f, aw = 0.f;

    int j0 = beg;
    while (j0 < end) {
        int m = end - j0; if (m > 64) m = 64;
        int   sl = (lane < m) ? rsrc[j0 + lane] : 0;
        float wl = (lane < m) ? rw[j0 + lane]   : 0.f;
        int t = 0;
        for (; t + 8 <= m; t += 8) {
            bf16x4 v[8]; float wv[8];
            #pragma unroll
            for (int u = 0; u < 8; ++u) {
                int s = __builtin_amdgcn_readlane(sl, t + u);
                wv[u] = __int_as_float(__builtin_amdgcn_readlane(__float_as_int(wl), t + u));
                v[u] = *reinterpret_cast<const bf16x4*>(xcol + (size_t)s * DFEAT);
            }
            #pragma unroll
            for (int u = 0; u < 8; ++u) {
                ax += wv[u] * (float)v[u][0];
                ay += wv[u] * (float)v[u][1];
                az += wv[u] * (float)v[u][2];
                aw += wv[u] * (float)v[u][3];
            }
        }
        for (; t < m; ++t) {
            int s = __builtin_amdgcn_readlane(sl, t);
            float wt = __int_as_float(__builtin_amdgcn_readlane(__float_as_int(wl), t));
            bf16x4 v = *reinterpret_cast<const bf16x4*>(xcol + (size_t)s * DFEAT);
            ax += wt * (float)v[0]; ay += wt * (float)v[1];
            az += wt * (float)v[2]; aw += wt * (float)v[3];
        }
        j0 += m;
    }

    float inv = (end > beg) ? 1.0f / (float)(end - beg) : 0.0f;
    bf16x4 o;
    o[0] = (__bf16)(ax * inv); o[1] = (__bf16)(ay * inv);
    o[2] = (__bf16)(az * inv); o[3] = (__bf16)(aw * inv);
    *reinterpret_cast<bf16x4*>(mean + (size_t)wid * DFEAT + lane * 4) = o;
}

// ---------------------------------------------------------------------------
// MFMA GEMM:  out[i,:] = epi( A[i,:]@Wl + B[i,:]@Wr + bias )   (unchanged R1)
// ---------------------------------------------------------------------------
template<int EPI>
__global__ __launch_bounds__(256) void gemm_mfma(
    const __bf16* __restrict__ A, const __bf16* __restrict__ B,
    const __bf16* __restrict__ WT, const float* __restrict__ bias,
    const __bf16* __restrict__ resid, void* __restrict__ outv, int n)
{
    __shared__ char sAb[64 * 256];

    const int tid  = threadIdx.x;
    const int lane = tid & 63;
    const int wv   = tid >> 6;
    const int lo   = lane & 15;
    const int hi   = lane >> 4;
    const int brow = blockIdx.x * 64;
    const int wcol = wv * 64;
    const int nm1  = n - 1;

    f32x4 acc[4][4];
    #pragma unroll
    for (int i = 0; i < 4; ++i)
        #pragma unroll
        for (int j = 0; j < 4; ++j) acc[i][j] = (f32x4){0.f, 0.f, 0.f, 0.f};

    for (int chunk = 0; chunk < 4; ++chunk) {
        const __bf16* mat = (chunk < 2) ? A : B;
        const int koff = (chunk & 1) * 256;
        #pragma unroll
        for (int q = 0; q < 4; ++q) {
            int p    = q * 256 + tid;
            int row  = p >> 4;
            int slot = p & 15;
            int grow = brow + row; if (grow > nm1) grow = nm1;
            int srcoff = (slot * 16) ^ ((row & 7) << 4);
            const char* g = reinterpret_cast<const char*>(mat) + (size_t)grow * 512 + koff + srcoff;
            char* l = sAb + p * 16;
            __builtin_amdgcn_global_load_lds(
                (const __attribute__((address_space(1))) void*)g,
                (__attribute__((address_space(3))) void*)l, 16, 0, 0);
        }
        __syncthreads();

        const size_t wkbase = (size_t)chunk * 128;
        #pragma unroll
        for (int kt = 0; kt < 4; ++kt) {
            bf16x8 bfr[4];
            #pragma unroll
            for (int nn = 0; nn < 4; ++nn) {
                const __bf16* bp = WT + (size_t)(wcol + nn * 16 + lo) * 512
                                      + wkbase + kt * 32 + hi * 8;
                bfr[nn] = *reinterpret_cast<const bf16x8*>(bp);
            }
            #pragma unroll
            for (int mm = 0; mm < 4; ++mm) {
                int rl = mm * 16 + lo;
                int kb = kt * 64 + hi * 16;
                const bf16x8 a = *reinterpret_cast<const bf16x8*>(
                    sAb + rl * 256 + (kb ^ ((rl & 7) << 4)));
                #pragma unroll
                for (int nn = 0; nn < 4; ++nn)
                    acc[mm][nn] = __builtin_amdgcn_mfma_f32_16x16x32_bf16(
                        a, bfr[nn], acc[mm][nn], 0, 0, 0);
            }
        }
        __syncthreads();
    }

    #pragma unroll
    for (int mm = 0; mm < 4; ++mm) {
        #pragma unroll
        for (int nn = 0; nn < 4; ++nn) {
            int col = wcol + nn * 16 + lo;
            float bv = bias[col];
            #pragma unroll
            for (int r = 0; r < 4; ++r) {
                int grow = brow + mm * 16 + hi * 4 + r;
                if (grow >= n) continue;
                float v = acc[mm][nn][r] + bv;
                if (EPI == 1) {
                    float rv = (float)resid[(size_t)grow * DFEAT + col];
                    ((__bf16*)outv)[(size_t)grow * DFEAT + col] =
                        (__bf16)(rv + fmaxf(v, 0.f));
                } else {
                    ((float*)outv)[(size_t)grow * DFEAT + col] = v;
                }
            }
        }
    }
}

// ---------------------------------------------------------------------------
extern "C" void kernel_launch(void* const* d_in, const int* in_sizes, int n_in,
                              void* d_out, int out_size, void* d_ws, size_t ws_size,
                              hipStream_t stream) {
    const float* x_user  = (const float*)d_in[0];
    const float* x_movie = (const float*)d_in[1];
    const int*   src_um  = (const int*)d_in[2];
    const int*   dst_um  = (const int*)d_in[3];
    const float* w_um    = (const float*)d_in[4];
    const int*   src_mu  = (const int*)d_in[5];
    const int*   dst_mu  = (const int*)d_in[6];
    const float* w_mu    = (const float*)d_in[7];
    const float* c1_um_Wl = (const float*)d_in[8];
    const float* c1_um_Wr = (const float*)d_in[9];
    const float* c1_um_b  = (const float*)d_in[10];
    const float* c1_mu_Wl = (const float*)d_in[11];
    const float* c1_mu_Wr = (const float*)d_in[12];
    const float* c1_mu_b  = (const float*)d_in[13];
    const float* c2_um_Wl = (const float*)d_in[14];
    const float* c2_um_Wr = (const float*)d_in[15];
    const float* c2_um_b  = (const float*)d_in[16];
    const float* c2_mu_Wl = (const float*)d_in[17];
    const float* c2_mu_Wr = (const float*)d_in[18];
    const float* c2_mu_b  = (const float*)d_in[19];

    const int NU = in_sizes[0] / DFEAT;   // 100000
    const int NM = in_sizes[1] / DFEAT;   // 20000
    const int E_um = in_sizes[2];         // 1M
    const int E_mu = in_sizes[5];         // 1M

    // ---- workspace carve ----
    char* p = (char*)d_ws;
    auto carve = [&](size_t bytes) { char* r = p; p += (bytes + 255) & ~(size_t)255; return r; };
    int* rowptr_m = (int*)carve((size_t)(NM + 1) * 4);
    int* rowptr_u = (int*)carve((size_t)(NU + 1) * 4);
    int* cursor_m = (int*)carve((size_t)NM * 4);
    int* cursor_u = (int*)carve((size_t)NU * 4);
    int* bsum_m   = (int*)carve(64 * 4);
    int* bsum_u   = (int*)carve(64 * 4);
    __bf16* xu_bf = (__bf16*)carve((size_t)NU * DFEAT * 2);  // later reused as mean2_user
    __bf16* xm_bf = (__bf16*)carve((size_t)NM * DFEAT * 2);  // later reused as mean2_movie
    __bf16* ru_bf = (__bf16*)carve((size_t)NU * DFEAT * 2);
    __bf16* rm_bf = (__bf16*)carve((size_t)NM * DFEAT * 2);
    __bf16* wt_c1um = (__bf16*)carve(256 * 512 * 2);
    __bf16* wt_c1mu = (__bf16*)carve(256 * 512 * 2);
    __bf16* wt_c2um = (__bf16*)carve(256 * 512 * 2);
    __bf16* wt_c2mu = (__bf16*)carve(256 * 512 * 2);

    // dst-sorted edge records live in the dead tail of d_out:
    //   mean1_u bf16 [0, 51.2MB) + mean1_m [51.2, 61.44MB); records [61.44, 77.44MB).
    //   Final f32 GEMM writes (out_user covers [0,102.4MB)) happen after last record use.
    char* dtail = (char*)d_out + (size_t)(NU + NM) * DFEAT * 2;
    int*   rsrc_m = (int*)  (dtail);
    float* rw_m   = (float*)(dtail + (size_t)E_um * 4);
    int*   rsrc_u = (int*)  (dtail + (size_t)E_um * 8);
    float* rw_u   = (float*)(dtail + (size_t)E_um * 8 + (size_t)E_mu * 4);

    __bf16* mean1_u = (__bf16*)d_out;
    __bf16* mean1_m = (__bf16*)d_out + (size_t)NU * DFEAT;
    float* out_user  = (float*)d_out;
    float* out_movie = (float*)d_out + (size_t)NU * DFEAT;

    // ---- CSR build (shared by both layers) ----
    hipMemsetAsync(rowptr_m, 0, (size_t)(NM + 1) * 4, stream);
    hipMemsetAsync(rowptr_u, 0, (size_t)(NU + 1) * 4, stream);
    hist_kernel<<<2048, 256, 0, stream>>>(dst_um, E_um, rowptr_m);
    hist_kernel<<<2048, 256, 0, stream>>>(dst_mu, E_mu, rowptr_u);
    const int nbM = (NM + 1 + 2047) / 2048;
    const int nbU = (NU + 1 + 2047) / 2048;
    scan_block<<<nbM, 256, 0, stream>>>(rowptr_m, NM + 1, bsum_m);
    scan_block<<<nbU, 256, 0, stream>>>(rowptr_u, NU + 1, bsum_u);
    scan_sums<<<1, 64, 0, stream>>>(bsum_m, nbM);
    scan_sums<<<1, 64, 0, stream>>>(bsum_u, nbU);
    scan_add<<<nbM, 256, 0, stream>>>(rowptr_m, NM + 1, bsum_m);
    scan_add<<<nbU, 256, 0, stream>>>(rowptr_u, NU + 1, bsum_u);
    copy_int<<<256, 256, 0, stream>>>(rowptr_m, cursor_m, NM);
    copy_int<<<256, 256, 0, stream>>>(rowptr_u, cursor_u, NU);
    fill_kernel<<<2048, 256, 0, stream>>>(dst_um, src_um, w_um, E_um, cursor_m, rsrc_m, rw_m);
    fill_kernel<<<2048, 256, 0, stream>>>(dst_mu, src_mu, w_mu, E_mu, cursor_u, rsrc_u, rw_u);

    // ---- precompute bf16 features + transposed weights ----
    f32_to_bf16_kernel<<<2048, 256, 0, stream>>>(x_user, xu_bf, NU * DFEAT / 8);
    f32_to_bf16_kernel<<<2048, 256, 0, stream>>>(x_movie, xm_bf, NM * DFEAT / 8);
    wtrans_kernel<<<512, 256, 0, stream>>>(c1_um_Wl, c1_um_Wr, wt_c1um);
    wtrans_kernel<<<512, 256, 0, stream>>>(c1_mu_Wl, c1_mu_Wr, wt_c1mu);
    wtrans_kernel<<<512, 256, 0, stream>>>(c2_um_Wl, c2_um_Wr, wt_c2um);
    wtrans_kernel<<<512, 256, 0, stream>>>(c2_mu_Wl, c2_mu_Wr, wt_c2mu);

    // ---- layer 1 ----
    aggregate_bf16<<<(NM + 3) / 4, 256, 0, stream>>>(xu_bf, rsrc_m, rw_m, rowptr_m, mean1_m, NM);
    aggregate_bf16<<<(NU + 3) / 4, 256, 0, stream>>>(xm_bf, rsrc_u, rw_u, rowptr_u, mean1_u, NU);
    gemm_mfma<1><<<(NM + 63) / 64, 256, 0, stream>>>(mean1_m, xm_bf, wt_c1um, c1_um_b, xm_bf, rm_bf, NM);
    gemm_mfma<1><<<(NU + 63) / 64, 256, 0, stream>>>(mean1_u, xu_bf, wt_c1mu, c1_mu_b, xu_bf, ru_bf, NU);

    // ---- layer 2 (means reuse the dead x_bf buffers) ----
    __bf16* mean2_m = xm_bf;
    __bf16* mean2_u = xu_bf;
    aggregate_bf16<<<(NM + 3) / 4, 256, 0, stream>>>(ru_bf, rsrc_m, rw_m, rowptr_m, mean2_m, NM);
    aggregate_bf16<<<(NU + 3) / 4, 256, 0, stream>>>(rm_bf, rsrc_u, rw_u, rowptr_u, mean2_u, NU);
    gemm_mfma<0><<<(NM + 63) / 64, 256, 0, stream>>>(mean2_m, rm_bf, wt_c2um, c2_um_b, nullptr, out_movie, NM);
    gemm_mfma<0><<<(NU + 63) / 64, 256, 0, stream>>>(mean2_u, ru_bf, wt_c2mu, c2_mu_b, nullptr, out_user, NU);
}

// Round 4
// 766.299 us; speedup vs baseline: 2.8620x; 1.0458x over previous
//
#include <hip/hip_runtime.h>
#include <hip/hip_bf16.h>

#define DFEAT 256

typedef __bf16 bf16x8 __attribute__((ext_vector_type(8)));
typedef __bf16 bf16x4 __attribute__((ext_vector_type(4)));
typedef float  f32x4  __attribute__((ext_vector_type(4)));

// ---------------------------------------------------------------------------
// CSR build: histogram -> hierarchical scan -> cursor scatter (sorted records)
// ---------------------------------------------------------------------------
__global__ void hist_kernel(const int* __restrict__ dst, int nE, int* __restrict__ P) {
    for (int e = blockIdx.x * blockDim.x + threadIdx.x; e < nE; e += gridDim.x * blockDim.x)
        atomicAdd(&P[dst[e] + 1], 1);
}

__global__ __launch_bounds__(256) void scan_block(int* __restrict__ a, int n, int* __restrict__ bsum) {
    __shared__ int wsum[4];
    const int tid = threadIdx.x;
    const int lane = tid & 63, wv = tid >> 6;
    const int idx = blockIdx.x * 2048 + tid * 8;
    int v[8];
    #pragma unroll
    for (int i = 0; i < 8; ++i) v[i] = (idx + i < n) ? a[idx + i] : 0;
    #pragma unroll
    for (int i = 1; i < 8; ++i) v[i] += v[i - 1];
    int tsum = v[7];
    int sc = tsum;
    #pragma unroll
    for (int off = 1; off < 64; off <<= 1) {
        int t = __shfl_up(sc, off);
        if (lane >= off) sc += t;
    }
    if (lane == 63) wsum[wv] = sc;
    __syncthreads();
    int wadd = 0;
    for (int w2 = 0; w2 < wv; ++w2) wadd += wsum[w2];
    int texcl = sc - tsum + wadd;
    #pragma unroll
    for (int i = 0; i < 8; ++i)
        if (idx + i < n) a[idx + i] = v[i] + texcl;
    if (tid == 255) bsum[blockIdx.x] = sc + wadd;
}

__global__ void scan_sums(int* __restrict__ bsum, int nb) {
    int lane = threadIdx.x;
    int v = (lane < nb) ? bsum[lane] : 0;
    #pragma unroll
    for (int off = 1; off < 64; off <<= 1) {
        int t = __shfl_up(v, off);
        if (lane >= off) v += t;
    }
    if (lane < nb) bsum[lane] = v;
}

__global__ __launch_bounds__(256) void scan_add(int* __restrict__ a, int n, const int* __restrict__ bsum) {
    if (blockIdx.x == 0) return;
    int add = bsum[blockIdx.x - 1];
    int idx = blockIdx.x * 2048 + threadIdx.x * 8;
    #pragma unroll
    for (int i = 0; i < 8; ++i)
        if (idx + i < n) a[idx + i] += add;
}

__global__ void copy_int(const int* __restrict__ src, int* __restrict__ dst, int n) {
    for (int i = blockIdx.x * blockDim.x + threadIdx.x; i < n; i += gridDim.x * blockDim.x)
        dst[i] = src[i];
}

__global__ void fill_kernel(const int* __restrict__ dst, const int* __restrict__ src,
                            const float* __restrict__ w, int nE,
                            int* __restrict__ cursor,
                            int* __restrict__ rsrc, float* __restrict__ rw) {
    for (int e = blockIdx.x * blockDim.x + threadIdx.x; e < nE; e += gridDim.x * blockDim.x) {
        int pos = atomicAdd(&cursor[dst[e]], 1);
        rsrc[pos] = src[e];
        rw[pos]   = w[e];
    }
}

// ---------------------------------------------------------------------------
__global__ __launch_bounds__(256) void f32_to_bf16_kernel(
    const float* __restrict__ in, __bf16* __restrict__ out, int n8)
{
    for (int i = blockIdx.x * blockDim.x + threadIdx.x; i < n8; i += gridDim.x * blockDim.x) {
        float4 a = *reinterpret_cast<const float4*>(in + (size_t)i * 8);
        float4 b = *reinterpret_cast<const float4*>(in + (size_t)i * 8 + 4);
        bf16x8 v;
        v[0] = (__bf16)a.x; v[1] = (__bf16)a.y; v[2] = (__bf16)a.z; v[3] = (__bf16)a.w;
        v[4] = (__bf16)b.x; v[5] = (__bf16)b.y; v[6] = (__bf16)b.z; v[7] = (__bf16)b.w;
        *reinterpret_cast<bf16x8*>(out + (size_t)i * 8) = v;
    }
}

// WcatT[n][k] bf16 [256][512]: k<256 -> Wl[k][n], k>=256 -> Wr[k-256][n]
__global__ __launch_bounds__(256) void wtrans_kernel(
    const float* __restrict__ Wl, const float* __restrict__ Wr, __bf16* __restrict__ out)
{
    int t = blockIdx.x * blockDim.x + threadIdx.x;
    if (t >= 256 * 512) return;
    int n = t >> 9;
    int k = t & 511;
    float v = (k < 256) ? Wl[(size_t)k * 256 + n] : Wr[(size_t)(k - 256) * 256 + n];
    out[t] = (__bf16)v;
}

// ---------------------------------------------------------------------------
// Aggregation: one wave per dst row; 2 edges per wave-step (32 lanes x 16B),
// 16 edges in flight; cross-half combine via shfl_xor(32).
// ---------------------------------------------------------------------------
__global__ __launch_bounds__(256) void aggregate_bf16(
    const __bf16* __restrict__ xsrc, const int* __restrict__ rsrc,
    const float* __restrict__ rw, const int* __restrict__ rowptr,
    __bf16* __restrict__ mean, int ndst)
{
    int wid  = (blockIdx.x * blockDim.x + threadIdx.x) >> 6;
    int lane = threadIdx.x & 63;
    if (wid >= ndst) return;
    int beg = rowptr[wid], end = rowptr[wid + 1];
    const int half = lane >> 5, hl = lane & 31;
    const __bf16* xcol = xsrc + hl * 8;
    float acc[8];
    #pragma unroll
    for (int i = 0; i < 8; ++i) acc[i] = 0.f;

    int j0 = beg;
    while (j0 < end) {
        int m = end - j0; if (m > 64) m = 64;
        int   sl = (lane < m) ? rsrc[j0 + lane] : 0;
        float wl = (lane < m) ? rw[j0 + lane]   : 0.f;
        int t = 0;
        for (; t + 16 <= m; t += 16) {          // 8 steps = 16 edges in flight
            bf16x8 v[8]; float wt[8];
            #pragma unroll
            for (int u = 0; u < 8; ++u) {
                int tt = t + u * 2;
                int e0 = __builtin_amdgcn_readlane(sl, tt);
                int e1 = __builtin_amdgcn_readlane(sl, tt + 1);
                int w0 = __builtin_amdgcn_readlane(__float_as_int(wl), tt);
                int w1 = __builtin_amdgcn_readlane(__float_as_int(wl), tt + 1);
                int s = half ? e1 : e0;
                wt[u] = __int_as_float(half ? w1 : w0);
                v[u] = *reinterpret_cast<const bf16x8*>(xcol + (size_t)s * DFEAT);
            }
            #pragma unroll
            for (int u = 0; u < 8; ++u)
                #pragma unroll
                for (int i = 0; i < 8; ++i) acc[i] += wt[u] * (float)v[u][i];
        }
        for (; t < m; t += 2) {                  // tail steps
            int e0 = __builtin_amdgcn_readlane(sl, t);
            int e1 = __builtin_amdgcn_readlane(sl, (t + 1 < 64) ? t + 1 : 63);
            int w0 = __builtin_amdgcn_readlane(__float_as_int(wl), t);
            int w1 = __builtin_amdgcn_readlane(__float_as_int(wl), (t + 1 < 64) ? t + 1 : 63);
            int s = half ? e1 : e0;
            float wv2 = __int_as_float(half ? w1 : w0);
            if (half && t + 1 >= m) wv2 = 0.f;
            bf16x8 v = *reinterpret_cast<const bf16x8*>(xcol + (size_t)s * DFEAT);
            #pragma unroll
            for (int i = 0; i < 8; ++i) acc[i] += wv2 * (float)v[i];
        }
        j0 += m;
    }

    #pragma unroll
    for (int i = 0; i < 8; ++i) acc[i] += __shfl_xor(acc[i], 32);
    float inv = (end > beg) ? 1.0f / (float)(end - beg) : 0.0f;
    if (half == 0) {
        bf16x8 o;
        #pragma unroll
        for (int i = 0; i < 8; ++i) o[i] = (__bf16)(acc[i] * inv);
        *reinterpret_cast<bf16x8*>(mean + (size_t)wid * DFEAT + hl * 8) = o;
    }
}

// ---------------------------------------------------------------------------
// Pipelined MFMA GEMM: out[i,:] = epi( A[i,:]@Wl + B[i,:]@Wr + bias )
// 512 thr = 8 waves (2m x 4n). Wave tile: MREP*16 rows x 64 cols. BM=MREP*32.
// K=512 as 8 chunks of BK=64; chunks 0-3 read Amat, 4-7 read Bmat.
// A and B(WT) both LDS-staged, A+B double-buffered; stage(c+1) issued before
// compute(c); one __syncthreads (implicit vmcnt0 drain) per chunk (T3-min).
// T2 XOR swizzle (byte ^ (row&7)<<4) on staging source + LDS reads.
// ---------------------------------------------------------------------------
template<int MREP, int EPI>
__global__ __launch_bounds__(512) void gemm_mfma(
    const __bf16* __restrict__ Amat, const __bf16* __restrict__ Bmat,
    const __bf16* __restrict__ WT, const float* __restrict__ bias,
    const __bf16* __restrict__ resid, void* __restrict__ outv, int n)
{
    constexpr int BM = MREP * 32;
    __shared__ char sA[2][BM * 128];      // [rows][64k] bf16
    __shared__ char sB[2][256 * 128];     // [n][64k] bf16

    const int tid  = threadIdx.x;
    const int lane = tid & 63;
    const int wv   = tid >> 6;
    const int wr   = wv >> 2;             // 0..1
    const int wc   = wv & 3;              // 0..3
    const int lo   = lane & 15;
    const int hi   = lane >> 4;
    const int brow = blockIdx.x * BM;
    const int nm1  = n - 1;

    f32x4 acc[MREP][4];
    #pragma unroll
    for (int i = 0; i < MREP; ++i)
        #pragma unroll
        for (int j = 0; j < 4; ++j) acc[i][j] = (f32x4){0.f, 0.f, 0.f, 0.f};

    auto stage = [&](int chunk, int buf) {
        const __bf16* mat = (chunk < 4) ? Amat : Bmat;
        const int kbyte = (chunk & 3) * 128;
        #pragma unroll
        for (int q = 0; q < MREP / 2; ++q) {            // A: BM*8/512 slots/thr
            int s = q * 512 + tid;
            int r = s >> 3, sub = s & 7;
            int grow = brow + r; if (grow > nm1) grow = nm1;
            int srcoff = (sub * 16) ^ ((r & 7) << 4);
            const char* g = reinterpret_cast<const char*>(mat) + (size_t)grow * 512 + kbyte + srcoff;
            __builtin_amdgcn_global_load_lds(
                (const __attribute__((address_space(1))) void*)g,
                (__attribute__((address_space(3))) void*)(sA[buf] + s * 16), 16, 0, 0);
        }
        #pragma unroll
        for (int q = 0; q < 4; ++q) {                    // B: 2048 slots
            int s = q * 512 + tid;
            int nr = s >> 3, sub = s & 7;
            int srcoff = (sub * 16) ^ ((nr & 7) << 4);
            const char* g = reinterpret_cast<const char*>(WT) + (size_t)nr * 1024 + chunk * 128 + srcoff;
            __builtin_amdgcn_global_load_lds(
                (const __attribute__((address_space(1))) void*)g,
                (__attribute__((address_space(3))) void*)(sB[buf] + s * 16), 16, 0, 0);
        }
    };

    stage(0, 0);
    __syncthreads();

    for (int c = 0; c < 8; ++c) {
        const int cur = c & 1;
        if (c < 7) stage(c + 1, cur ^ 1);
        #pragma unroll
        for (int ks = 0; ks < 2; ++ks) {
            const int kb = ks * 64 + hi * 16;
            bf16x8 bfr[4];
            #pragma unroll
            for (int nn = 0; nn < 4; ++nn) {
                int nr = wc * 64 + nn * 16 + lo;
                bfr[nn] = *reinterpret_cast<const bf16x8*>(
                    sB[cur] + nr * 128 + (kb ^ ((nr & 7) << 4)));
            }
            #pragma unroll
            for (int mm = 0; mm < MREP; ++mm) {
                int r = wr * MREP * 16 + mm * 16 + lo;
                bf16x8 a = *reinterpret_cast<const bf16x8*>(
                    sA[cur] + r * 128 + (kb ^ ((r & 7) << 4)));
                #pragma unroll
                for (int nn = 0; nn < 4; ++nn)
                    acc[mm][nn] = __builtin_amdgcn_mfma_f32_16x16x32_bf16(
                        a, bfr[nn], acc[mm][nn], 0, 0, 0);
            }
        }
        __syncthreads();   // drains vmcnt (next chunk staged) + lgkm
    }

    // epilogue: D col = lane&15, row = (lane>>4)*4 + reg
    #pragma unroll
    for (int mm = 0; mm < MREP; ++mm) {
        #pragma unroll
        for (int nn = 0; nn < 4; ++nn) {
            int col = wc * 64 + nn * 16 + lo;
            float bv = bias[col];
            #pragma unroll
            for (int r = 0; r < 4; ++r) {
                int grow = brow + wr * MREP * 16 + mm * 16 + hi * 4 + r;
                if (grow >= n) continue;
                float v = acc[mm][nn][r] + bv;
                if (EPI == 1) {
                    float rv = (float)resid[(size_t)grow * DFEAT + col];
                    ((__bf16*)outv)[(size_t)grow * DFEAT + col] =
                        (__bf16)(rv + fmaxf(v, 0.f));
                } else {
                    ((float*)outv)[(size_t)grow * DFEAT + col] = v;
                }
            }
        }
    }
}

// ---------------------------------------------------------------------------
extern "C" void kernel_launch(void* const* d_in, const int* in_sizes, int n_in,
                              void* d_out, int out_size, void* d_ws, size_t ws_size,
                              hipStream_t stream) {
    const float* x_user  = (const float*)d_in[0];
    const float* x_movie = (const float*)d_in[1];
    const int*   src_um  = (const int*)d_in[2];
    const int*   dst_um  = (const int*)d_in[3];
    const float* w_um    = (const float*)d_in[4];
    const int*   src_mu  = (const int*)d_in[5];
    const int*   dst_mu  = (const int*)d_in[6];
    const float* w_mu    = (const float*)d_in[7];
    const float* c1_um_Wl = (const float*)d_in[8];
    const float* c1_um_Wr = (const float*)d_in[9];
    const float* c1_um_b  = (const float*)d_in[10];
    const float* c1_mu_Wl = (const float*)d_in[11];
    const float* c1_mu_Wr = (const float*)d_in[12];
    const float* c1_mu_b  = (const float*)d_in[13];
    const float* c2_um_Wl = (const float*)d_in[14];
    const float* c2_um_Wr = (const float*)d_in[15];
    const float* c2_um_b  = (const float*)d_in[16];
    const float* c2_mu_Wl = (const float*)d_in[17];
    const float* c2_mu_Wr = (const float*)d_in[18];
    const float* c2_mu_b  = (const float*)d_in[19];

    const int NU = in_sizes[0] / DFEAT;
    const int NM = in_sizes[1] / DFEAT;
    const int E_um = in_sizes[2];
    const int E_mu = in_sizes[5];

    char* p = (char*)d_ws;
    auto carve = [&](size_t bytes) { char* r = p; p += (bytes + 255) & ~(size_t)255; return r; };
    int* rowptr_m = (int*)carve((size_t)(NM + 1) * 4);
    int* rowptr_u = (int*)carve((size_t)(NU + 1) * 4);
    int* cursor_m = (int*)carve((size_t)NM * 4);
    int* cursor_u = (int*)carve((size_t)NU * 4);
    int* bsum_m   = (int*)carve(64 * 4);
    int* bsum_u   = (int*)carve(64 * 4);
    __bf16* xu_bf = (__bf16*)carve((size_t)NU * DFEAT * 2);
    __bf16* xm_bf = (__bf16*)carve((size_t)NM * DFEAT * 2);
    __bf16* ru_bf = (__bf16*)carve((size_t)NU * DFEAT * 2);
    __bf16* rm_bf = (__bf16*)carve((size_t)NM * DFEAT * 2);
    __bf16* wt_c1um = (__bf16*)carve(256 * 512 * 2);
    __bf16* wt_c1mu = (__bf16*)carve(256 * 512 * 2);
    __bf16* wt_c2um = (__bf16*)carve(256 * 512 * 2);
    __bf16* wt_c2mu = (__bf16*)carve(256 * 512 * 2);

    char* dtail = (char*)d_out + (size_t)(NU + NM) * DFEAT * 2;
    int*   rsrc_m = (int*)  (dtail);
    float* rw_m   = (float*)(dtail + (size_t)E_um * 4);
    int*   rsrc_u = (int*)  (dtail + (size_t)E_um * 8);
    float* rw_u   = (float*)(dtail + (size_t)E_um * 8 + (size_t)E_mu * 4);

    __bf16* mean1_u = (__bf16*)d_out;
    __bf16* mean1_m = (__bf16*)d_out + (size_t)NU * DFEAT;
    float* out_user  = (float*)d_out;
    float* out_movie = (float*)d_out + (size_t)NU * DFEAT;

    // ---- CSR build ----
    hipMemsetAsync(rowptr_m, 0, (size_t)(NM + 1) * 4, stream);
    hipMemsetAsync(rowptr_u, 0, (size_t)(NU + 1) * 4, stream);
    hist_kernel<<<2048, 256, 0, stream>>>(dst_um, E_um, rowptr_m);
    hist_kernel<<<2048, 256, 0, stream>>>(dst_mu, E_mu, rowptr_u);
    const int nbM = (NM + 1 + 2047) / 2048;
    const int nbU = (NU + 1 + 2047) / 2048;
    scan_block<<<nbM, 256, 0, stream>>>(rowptr_m, NM + 1, bsum_m);
    scan_block<<<nbU, 256, 0, stream>>>(rowptr_u, NU + 1, bsum_u);
    scan_sums<<<1, 64, 0, stream>>>(bsum_m, nbM);
    scan_sums<<<1, 64, 0, stream>>>(bsum_u, nbU);
    scan_add<<<nbM, 256, 0, stream>>>(rowptr_m, NM + 1, bsum_m);
    scan_add<<<nbU, 256, 0, stream>>>(rowptr_u, NU + 1, bsum_u);
    copy_int<<<256, 256, 0, stream>>>(rowptr_m, cursor_m, NM);
    copy_int<<<256, 256, 0, stream>>>(rowptr_u, cursor_u, NU);
    fill_kernel<<<2048, 256, 0, stream>>>(dst_um, src_um, w_um, E_um, cursor_m, rsrc_m, rw_m);
    fill_kernel<<<2048, 256, 0, stream>>>(dst_mu, src_mu, w_mu, E_mu, cursor_u, rsrc_u, rw_u);

    // ---- bf16 features + transposed weights ----
    f32_to_bf16_kernel<<<2048, 256, 0, stream>>>(x_user, xu_bf, NU * DFEAT / 8);
    f32_to_bf16_kernel<<<2048, 256, 0, stream>>>(x_movie, xm_bf, NM * DFEAT / 8);
    wtrans_kernel<<<512, 256, 0, stream>>>(c1_um_Wl, c1_um_Wr, wt_c1um);
    wtrans_kernel<<<512, 256, 0, stream>>>(c1_mu_Wl, c1_mu_Wr, wt_c1mu);
    wtrans_kernel<<<512, 256, 0, stream>>>(c2_um_Wl, c2_um_Wr, wt_c2um);
    wtrans_kernel<<<512, 256, 0, stream>>>(c2_mu_Wl, c2_mu_Wr, wt_c2mu);

    // ---- layer 1 ----
    aggregate_bf16<<<(NM + 3) / 4, 256, 0, stream>>>(xu_bf, rsrc_m, rw_m, rowptr_m, mean1_m, NM);
    aggregate_bf16<<<(NU + 3) / 4, 256, 0, stream>>>(xm_bf, rsrc_u, rw_u, rowptr_u, mean1_u, NU);
    gemm_mfma<2, 1><<<(NM + 63) / 64, 512, 0, stream>>>(mean1_m, xm_bf, wt_c1um, c1_um_b, xm_bf, rm_bf, NM);
    gemm_mfma<6, 1><<<(NU + 191) / 192, 512, 0, stream>>>(mean1_u, xu_bf, wt_c1mu, c1_mu_b, xu_bf, ru_bf, NU);

    // ---- layer 2 ----
    __bf16* mean2_m = xm_bf;
    __bf16* mean2_u = xu_bf;
    aggregate_bf16<<<(NM + 3) / 4, 256, 0, stream>>>(ru_bf, rsrc_m, rw_m, rowptr_m, mean2_m, NM);
    aggregate_bf16<<<(NU + 3) / 4, 256, 0, stream>>>(rm_bf, rsrc_u, rw_u, rowptr_u, mean2_u, NU);
    gemm_mfma<2, 0><<<(NM + 63) / 64, 512, 0, stream>>>(mean2_m, rm_bf, wt_c2um, c2_um_b, nullptr, out_movie, NM);
    gemm_mfma<6, 0><<<(NU + 191) / 192, 512, 0, stream>>>(mean2_u, ru_bf, wt_c2mu, c2_mu_b, nullptr, out_user, NU);
}